// Round 11
// baseline (95.619 us; speedup 1.0000x reference)
//
#include <hip/hip_runtime.h>
#include <hip/hip_fp8.h>

// NCE loss: out0 = align + w*uniform, out1 = align, out2 = uniform
// align[n]   = logsig(ref[n]·pos[n]/T)
// uniform[n] = mean_m logsig(-ref[n]·neg[m]/T)
// N=M=8192, D=512, T=0.5, w=1.0
//
// Round 11: MX-fp8 (e4m3, scale=1.0) 16x16x128. 256x256 tile, 8 waves,
// 4 K-tiles of 128, TWO phases per K-tile (16 MFMA per cluster) so the
// MFMA issue span covers the LDS-read drain; counted vmcnt ledger
// (phA=4, phB=2), setprio, proven chunk^(row&7) swizzle.

typedef __attribute__((ext_vector_type(4)))  float f32x4;
typedef __attribute__((ext_vector_type(4)))  int   int4v;
typedef __attribute__((ext_vector_type(8)))  int   int8v;
typedef __attribute__((ext_vector_type(16))) unsigned char uchar16;

constexpr int N_ = 8192;
constexpr int M_ = 8192;
constexpr int D_ = 512;
constexpr float INV_T = 2.0f;
constexpr float NEG_W = 1.0f;
constexpr float LOG2E = 1.4426950408889634f;
constexpr float LN2   = 0.6931471805599453f;
constexpr unsigned SCALE1 = 0x7F7F7F7Fu;  // E8M0 127 -> 2^0

__device__ __forceinline__ float logsig_neg(float s) {
  float t = __builtin_fabsf(s);
  float e = __builtin_amdgcn_exp2f(-t * LOG2E);
  float l = __builtin_amdgcn_logf(1.0f + e) * LN2;
  return fminf(-s, 0.0f) - l;
}

// fp32 -> fp8 e4m3 with intra-row 16B-chunk XOR involution pre-applied
// (row = 512B = 4 x 128B K-segments; chunk c stored at c ^ (row&7)).
__global__ __launch_bounds__(256) void cvt_pack(
    const float* __restrict__ refp, const float* __restrict__ negp,
    unsigned char* __restrict__ a8, unsigned char* __restrict__ b8) {
  const int b = blockIdx.x;
  const float* src = (b < 1024) ? refp : negp;
  unsigned char* dst = (b < 1024) ? a8 : b8;
  const int i = (b & 1023) * 256 + threadIdx.x;  // 16B-chunk index
  const float* s = src + (size_t)i * 16;
  uchar16 o;
#pragma unroll
  for (int j = 0; j < 16; ++j) {
    __hip_fp8_e4m3 q(s[j]);
    o[j] = q.__x;
  }
  const unsigned int row = (unsigned int)i >> 5;
  const unsigned int seg = ((unsigned int)i >> 3) & 3;
  const unsigned int c   = (unsigned int)i & 7;
  const size_t byte =
      (size_t)row * 512 + seg * 128 + (size_t)((c ^ (row & 7u)) << 4);
  *reinterpret_cast<uchar16*>(dst + byte) = o;
}

__global__ __launch_bounds__(512, 2) void nce_gemm(
    const unsigned char* __restrict__ A,  // ref fp8, pre-swizzled rows
    const unsigned char* __restrict__ B,  // neg fp8, pre-swizzled rows
    float* __restrict__ rowsum) {         // (N,) fp32, pre-zeroed
  extern __shared__ char lds[];
  char* As = lds;           // 2 bufs x 256 rows x 128 B
  char* Bs = lds + 65536;

  const int tid  = threadIdx.x;
  const int lane = tid & 63;
  const int wid  = tid >> 6;   // 0..7
  const int wr   = wid >> 2;   // 0..1 (A half: 128 rows)
  const int wc   = wid & 3;    // 0..3 (B quarter: 64 cols)

  // XCD band swizzle: 1024 blocks, 8 XCDs, 4 row-bands/XCD, col-major in band
  const int bid  = blockIdx.x;
  const int x    = bid & 7;
  const int t    = bid >> 3;
  const int brow = (x * 4 + (t & 3)) * 256;
  const int bcol = (t >> 2) * 256;

  const size_t laneoff = (size_t)(lane >> 3) * 512 + (size_t)(lane & 7) * 16;
  const char* gA = reinterpret_cast<const char*>(A) + (size_t)brow * 512 + laneoff;
  const char* gB = reinterpret_cast<const char*>(B) + (size_t)bcol * 512 + laneoff;

  // fragment constants: lane holds row (lane&15), K-bytes [(lane>>4)*32,+32)
  const int r  = lane & 15;
  const int g4 = lane >> 4;
  const int c0 = (((2 * g4) ^ (r & 7)) << 4);
  const int c1 = (((2 * g4 + 1) ^ (r & 7)) << 4);

  f32x4 acc[8][4] = {};
  int8v aF[8], bv0[2], bv1[2];

  // ---- stage one half-tile (16 KiB), 2 glds per thread ----
#define STAGE_A(g, h)                                                         \
  {                                                                           \
    _Pragma("unroll") for (int j = 0; j < 2; ++j) {                           \
      const int u  = wid * 2 + j;                                             \
      const int rb = (u >> 3) * 128 + (u & 7) * 8 + (h) * 64;                 \
      __builtin_amdgcn_global_load_lds(                                       \
          (const __attribute__((address_space(1))) unsigned int*)(            \
              gA + (size_t)rb * 512 + (size_t)((g) & 3) * 128),               \
          (__attribute__((address_space(3))) unsigned int*)(                  \
              As + ((g) & 1) * 32768 + rb * 128),                             \
          16, 0, 0);                                                          \
    }                                                                         \
  }
#define STAGE_B(g, h)                                                         \
  {                                                                           \
    _Pragma("unroll") for (int j = 0; j < 2; ++j) {                           \
      const int u  = wid * 2 + j;                                             \
      const int rb = (u >> 2) * 64 + (u & 3) * 8 + (h) * 32;                  \
      __builtin_amdgcn_global_load_lds(                                       \
          (const __attribute__((address_space(1))) unsigned int*)(            \
              gB + (size_t)rb * 512 + (size_t)((g) & 3) * 128),               \
          (__attribute__((address_space(3))) unsigned int*)(                  \
              Bs + ((g) & 1) * 32768 + rb * 128),                             \
          16, 0, 0);                                                          \
    }                                                                         \
  }

#define FRAG(base, ro, DSTV)                                                  \
  {                                                                           \
    int4v lo_ = *reinterpret_cast<const int4v*>((base) + (ro) + c0);          \
    int4v hi_ = *reinterpret_cast<const int4v*>((base) + (ro) + c1);          \
    DSTV = __builtin_shufflevector(lo_, hi_, 0, 1, 2, 3, 4, 5, 6, 7);         \
  }
  // all 8 A-fragments (m0: mf 0-3, m1: mf 4-7)
#define READ_A_ALL(buf)                                                       \
  {                                                                           \
    _Pragma("unroll") for (int mf = 0; mf < 8; ++mf) {                        \
      const int ro = (wr * 128 + mf * 16 + r) * 128;                          \
      FRAG(As + (buf)*32768, ro, aF[mf]);                                     \
    }                                                                         \
  }
#define READ_B(buf, nh, DST)                                                  \
  {                                                                           \
    _Pragma("unroll") for (int nf = 0; nf < 2; ++nf) {                        \
      const int ro = (wc * 64 + (nh)*32 + nf * 16 + r) * 128;                 \
      FRAG(Bs + (buf)*32768, ro, DST[nf]);                                    \
    }                                                                         \
  }

#define WB4() asm volatile("s_waitcnt vmcnt(4)\n\ts_barrier" ::: "memory")
#define WB2() asm volatile("s_waitcnt vmcnt(2)\n\ts_barrier" ::: "memory")
#define WB0() asm volatile("s_waitcnt vmcnt(0)\n\ts_barrier" ::: "memory")
#define BAR() asm volatile("s_barrier" ::: "memory")

  // 16 MFMA: all 8 m-frags x 2 n-frags of half nh
#define CLUSTER16(nh, BV)                                                     \
  {                                                                           \
    __builtin_amdgcn_s_setprio(1);                                            \
    _Pragma("unroll") for (int mf = 0; mf < 8; ++mf)                          \
    _Pragma("unroll") for (int nf = 0; nf < 2; ++nf)                          \
      acc[mf][(nh)*2 + nf] =                                                  \
          __builtin_amdgcn_mfma_scale_f32_16x16x128_f8f6f4(                   \
              aF[mf], BV[nf], acc[mf][(nh)*2 + nf], 0, 0,                     \
              0, SCALE1, 0, SCALE1);                                          \
    __builtin_amdgcn_s_setprio(0);                                            \
  }

  // ---- prologue: K-tile 0 (8 glds: A h0,h1, B h0,h1) ----
  STAGE_A(0, 0);
  STAGE_A(0, 1);
  STAGE_B(0, 0);
  STAGE_B(0, 1);
  WB2();  // retires A(0) full + B(0)h0; B(0)h1 in flight

  // ---- main loop: 4 K-tiles x {phA, phB} ----
#pragma unroll
  for (int e = 0; e < 4; ++e) {
    const int buf = e & 1;
    // phA: n-half 0
    READ_A_ALL(buf);
    READ_B(buf, 0, bv0);
    if (e < 3) {
      STAGE_A(e + 1, 0);
      STAGE_A(e + 1, 1);
      WB4();  // retires B(e)h1 -> phB read safe
    } else {
      WB0();  // tail: retire B(3)h1
    }
    CLUSTER16(0, bv0);
    // phB: n-half 1
    READ_B(buf, 1, bv1);
    if (e < 3) {
      STAGE_B(e + 1, 0);
      STAGE_B(e + 1, 1);
      WB2();  // retires A(e+1) full + B(e+1)h0 -> next phA reads safe
    } else {
      BAR();  // tail: nothing in flight
    }
    CLUSTER16(1, bv1);
  }
#undef STAGE_A
#undef STAGE_B
#undef FRAG
#undef READ_A_ALL
#undef READ_B
#undef CLUSTER16

  // ---- epilogue: uni = logsig(-s*INV_T); reduce this wave's 64 cols ----
  float part[32];
#pragma unroll
  for (int am = 0; am < 8; ++am)
#pragma unroll
    for (int rr = 0; rr < 4; ++rr) {
      float ssum = 0.0f;
#pragma unroll
      for (int an = 0; an < 4; ++an) {
        float s = acc[am][an][rr] * INV_T;
        ssum += logsig_neg(s);
      }
      part[am * 4 + rr] = ssum;
    }
#pragma unroll
  for (int i = 0; i < 32; ++i) {
    float v = part[i];
    v += __shfl_xor(v, 1);
    v += __shfl_xor(v, 2);
    v += __shfl_xor(v, 4);
    v += __shfl_xor(v, 8);
    part[i] = v;
  }
  if ((lane & 15) == 0) {
    const int gq = lane >> 4;
#pragma unroll
    for (int am = 0; am < 8; ++am)
#pragma unroll
      for (int rr = 0; rr < 4; ++rr)
        atomicAdd(&rowsum[brow + wr * 128 + am * 16 + gq * 4 + rr],
                  part[am * 4 + rr]);
  }
}

__global__ __launch_bounds__(256) void nce_combine(
    const float* __restrict__ ref, const float* __restrict__ pos,
    const float* __restrict__ rowsum, float* __restrict__ out) {
  const int wid  = threadIdx.x >> 6;
  const int lane = threadIdx.x & 63;
  const int n    = blockIdx.x * 4 + wid;

  const f32x4* pr =
      reinterpret_cast<const f32x4*>(ref + (size_t)n * D_ + lane * 8);
  const f32x4* pp =
      reinterpret_cast<const f32x4*>(pos + (size_t)n * D_ + lane * 8);
  f32x4 a0 = pr[0], a1 = pr[1], b0 = pp[0], b1 = pp[1];
  float d = 0.0f;
#pragma unroll
  for (int i = 0; i < 4; ++i) d = __builtin_fmaf(a0[i], b0[i], d);
#pragma unroll
  for (int i = 0; i < 4; ++i) d = __builtin_fmaf(a1[i], b1[i], d);
#pragma unroll
  for (int s = 1; s < 64; s <<= 1) d += __shfl_xor(d, s);

  if (lane == 0) {
    float z = d * INV_T;
    float align   = logsig_neg(-z);
    float uniform = rowsum[n] * (1.0f / (float)M_);
    out[n]          = align + NEG_W * uniform;
    out[N_ + n]     = align;
    out[2 * N_ + n] = uniform;
  }
}

extern "C" void kernel_launch(void* const* d_in, const int* in_sizes, int n_in,
                              void* d_out, int out_size, void* d_ws,
                              size_t ws_size, hipStream_t stream) {
  const float* ref = (const float*)d_in[0];
  const float* pos = (const float*)d_in[1];
  const float* neg = (const float*)d_in[2];
  float* out = (float*)d_out;

  float* rowsum = (float*)d_ws;                                   // 32 KB
  unsigned char* a8 = (unsigned char*)d_ws + 32768;               // 4 MB
  unsigned char* b8 = a8 + (size_t)N_ * D_;                       // 4 MB

  (void)hipFuncSetAttribute((const void*)nce_gemm,
                            hipFuncAttributeMaxDynamicSharedMemorySize,
                            131072);

  hipMemsetAsync(rowsum, 0, N_ * sizeof(float), stream);
  cvt_pack<<<2048, 256, 0, stream>>>(ref, neg, a8, b8);
  nce_gemm<<<1024, 512, 131072, stream>>>(a8, b8, rowsum);
  nce_combine<<<N_ / 4, 256, 0, stream>>>(ref, pos, rowsum, out);
}

// Round 12
// 86.220 us; speedup vs baseline: 1.1090x; 1.1090x over previous
//
#include <hip/hip_runtime.h>
#include <hip/hip_fp8.h>

// NCE loss: out0 = align + w*uniform, out1 = align, out2 = uniform
// align[n]   = logsig(ref[n]·pos[n]/T)
// uniform[n] = mean_m logsig(-ref[n]·neg[m]/T)
// N=M=8192, D=512, T=0.5, w=1.0
//
// Round 12: MX-fp8 (e4m3, scale=1.0) 16x16x128, m97/m148-style 128x128
// tile, 4 waves, BK=128, double-buffered 64KB LDS -> 2 blocks/CU.
// Cross-block overlap replaces hand pipelining: one __syncthreads per
// K-tile, prefetch issued before compute. Pre-swizzled fp8 global
// (chunk ^ (row&7) within each 128B K-segment), conflict-free 16-lane
// fragment reads, 8-band column-major XCD walk.

typedef __attribute__((ext_vector_type(4)))  float f32x4;
typedef __attribute__((ext_vector_type(4)))  int   int4v;
typedef __attribute__((ext_vector_type(8)))  int   int8v;
typedef __attribute__((ext_vector_type(16))) unsigned char uchar16;

constexpr int N_ = 8192;
constexpr int M_ = 8192;
constexpr int D_ = 512;
constexpr float INV_T = 2.0f;
constexpr float NEG_W = 1.0f;
constexpr float LOG2E = 1.4426950408889634f;
constexpr float LN2   = 0.6931471805599453f;
constexpr unsigned SCALE1 = 0x7F7F7F7Fu;  // E8M0 127 -> 2^0 = 1.0

__device__ __forceinline__ float logsig_neg(float s) {
  float t = __builtin_fabsf(s);
  float e = __builtin_amdgcn_exp2f(-t * LOG2E);
  float l = __builtin_amdgcn_logf(1.0f + e) * LN2;
  return fminf(-s, 0.0f) - l;
}

// fp32 -> fp8 e4m3 with intra-row 16B-chunk XOR involution pre-applied
// (row = 512B = 4 x 128B K-segments; chunk c stored at c ^ (row&7)).
__global__ __launch_bounds__(256) void cvt_pack(
    const float* __restrict__ refp, const float* __restrict__ negp,
    unsigned char* __restrict__ a8, unsigned char* __restrict__ b8) {
  const int b = blockIdx.x;
  const float* src = (b < 1024) ? refp : negp;
  unsigned char* dst = (b < 1024) ? a8 : b8;
  const int i = (b & 1023) * 256 + threadIdx.x;  // 16B-chunk index
  const float* s = src + (size_t)i * 16;
  uchar16 o;
#pragma unroll
  for (int j = 0; j < 16; ++j) {
    __hip_fp8_e4m3 q(s[j]);
    o[j] = q.__x;
  }
  const unsigned int row = (unsigned int)i >> 5;
  const unsigned int seg = ((unsigned int)i >> 3) & 3;
  const unsigned int c   = (unsigned int)i & 7;
  const size_t byte =
      (size_t)row * 512 + seg * 128 + (size_t)((c ^ (row & 7u)) << 4);
  *reinterpret_cast<uchar16*>(dst + byte) = o;
}

__global__ __launch_bounds__(256, 2) void nce_gemm(
    const unsigned char* __restrict__ A,  // ref fp8, pre-swizzled rows
    const unsigned char* __restrict__ B,  // neg fp8, pre-swizzled rows
    float* __restrict__ rowsum) {         // (N,) fp32, pre-zeroed
  // 2 bufs x (A 128x128B + B 128x128B) = 64 KiB -> 2 blocks/CU
  __shared__ __align__(16) char As[2][128 * 128];
  __shared__ __align__(16) char Bs[2][128 * 128];

  const int tid  = threadIdx.x;
  const int lane = tid & 63;
  const int wid  = tid >> 6;   // 0..3
  const int wr   = wid >> 1;   // 0..1 (A half: 64 rows)
  const int wc   = wid & 1;    // 0..1 (B half: 64 cols)

  // XCD swizzle: 4096 blocks, 8 XCDs, 8-row bands, column-major in band
  const int bid  = blockIdx.x;
  const int x    = bid & 7;
  const int t    = bid >> 3;   // 0..511
  const int brow = (x * 8 + (t & 7)) * 128;
  const int bcol = (t >> 3) * 128;

  // staging lane address (global stored layout == desired LDS layout)
  const size_t laneoff = (size_t)(lane >> 3) * 512 + (size_t)(lane & 7) * 16;
  const char* gA = reinterpret_cast<const char*>(A) + (size_t)brow * 512 + laneoff;
  const char* gB = reinterpret_cast<const char*>(B) + (size_t)bcol * 512 + laneoff;

  // fragment constants: lane holds row (lane&15), K-bytes [(lane>>4)*32,+32)
  const int r  = lane & 15;
  const int g4 = lane >> 4;
  const int c0 = (((2 * g4) ^ (r & 7)) << 4);
  const int c1 = c0 ^ 16;

  f32x4 acc[4][4] = {};
  int8v aF[4], bF[4];

  // stage one full 128x128B tile of A and B (wave w: rows [w*32, w*32+32))
#define STAGE(kt, buf)                                                        \
  {                                                                           \
    _Pragma("unroll") for (int j = 0; j < 4; ++j) {                           \
      const int rb = wid * 32 + j * 8;                                        \
      __builtin_amdgcn_global_load_lds(                                       \
          (const __attribute__((address_space(1))) unsigned int*)(            \
              gA + (size_t)rb * 512 + (size_t)(kt) * 128),                    \
          (__attribute__((address_space(3))) unsigned int*)(                  \
              &As[buf][rb * 128]),                                            \
          16, 0, 0);                                                          \
      __builtin_amdgcn_global_load_lds(                                       \
          (const __attribute__((address_space(1))) unsigned int*)(            \
              gB + (size_t)rb * 512 + (size_t)(kt) * 128),                    \
          (__attribute__((address_space(3))) unsigned int*)(                  \
              &Bs[buf][rb * 128]),                                            \
          16, 0, 0);                                                          \
    }                                                                         \
  }

#define FRAG(base, ro, DSTV)                                                  \
  {                                                                           \
    int4v lo_ = *reinterpret_cast<const int4v*>((base) + (ro) + c0);          \
    int4v hi_ = *reinterpret_cast<const int4v*>((base) + (ro) + c1);          \
    DSTV = __builtin_shufflevector(lo_, hi_, 0, 1, 2, 3, 4, 5, 6, 7);         \
  }

  // ---- prologue ----
  STAGE(0, 0);
  __syncthreads();

  // ---- main loop: 4 K-tiles of 128 ----
#pragma unroll
  for (int kt = 0; kt < 4; ++kt) {
    const int cur = kt & 1;
    if (kt + 1 < 4) STAGE(kt + 1, cur ^ 1);  // prefetch overlaps compute

#pragma unroll
    for (int mf = 0; mf < 4; ++mf) {
      const int ro = (wr * 64 + mf * 16 + r) * 128;
      FRAG(As[cur], ro, aF[mf]);
    }
#pragma unroll
    for (int nf = 0; nf < 4; ++nf) {
      const int ro = (wc * 64 + nf * 16 + r) * 128;
      FRAG(Bs[cur], ro, bF[nf]);
    }

    __builtin_amdgcn_s_setprio(1);
#pragma unroll
    for (int mf = 0; mf < 4; ++mf)
#pragma unroll
      for (int nf = 0; nf < 4; ++nf)
        acc[mf][nf] = __builtin_amdgcn_mfma_scale_f32_16x16x128_f8f6f4(
            aF[mf], bF[nf], acc[mf][nf], 0, 0, 0, SCALE1, 0, SCALE1);
    __builtin_amdgcn_s_setprio(0);

    __syncthreads();  // drains vmcnt(0): staged tile ready; LDS reads done
  }
#undef STAGE
#undef FRAG

  // ---- epilogue: uni = logsig(-s*INV_T); reduce this wave's 64 cols ----
  float part[16];
#pragma unroll
  for (int mf = 0; mf < 4; ++mf)
#pragma unroll
    for (int rr = 0; rr < 4; ++rr) {
      float ssum = 0.0f;
#pragma unroll
      for (int nf = 0; nf < 4; ++nf) {
        float s = acc[mf][nf][rr] * INV_T;
        ssum += logsig_neg(s);
      }
      part[mf * 4 + rr] = ssum;
    }
#pragma unroll
  for (int i = 0; i < 16; ++i) {
    float v = part[i];
    v += __shfl_xor(v, 1);
    v += __shfl_xor(v, 2);
    v += __shfl_xor(v, 4);
    v += __shfl_xor(v, 8);
    part[i] = v;
  }
  if ((lane & 15) == 0) {
#pragma unroll
    for (int mf = 0; mf < 4; ++mf)
#pragma unroll
      for (int rr = 0; rr < 4; ++rr)
        atomicAdd(&rowsum[brow + wr * 64 + mf * 16 + g4 * 4 + rr],
                  part[mf * 4 + rr]);
  }
}

__global__ __launch_bounds__(256) void nce_combine(
    const float* __restrict__ ref, const float* __restrict__ pos,
    const float* __restrict__ rowsum, float* __restrict__ out) {
  const int wid  = threadIdx.x >> 6;
  const int lane = threadIdx.x & 63;
  const int n    = blockIdx.x * 4 + wid;

  const f32x4* pr =
      reinterpret_cast<const f32x4*>(ref + (size_t)n * D_ + lane * 8);
  const f32x4* pp =
      reinterpret_cast<const f32x4*>(pos + (size_t)n * D_ + lane * 8);
  f32x4 a0 = pr[0], a1 = pr[1], b0 = pp[0], b1 = pp[1];
  float d = 0.0f;
#pragma unroll
  for (int i = 0; i < 4; ++i) d = __builtin_fmaf(a0[i], b0[i], d);
#pragma unroll
  for (int i = 0; i < 4; ++i) d = __builtin_fmaf(a1[i], b1[i], d);
#pragma unroll
  for (int s = 1; s < 64; s <<= 1) d += __shfl_xor(d, s);

  if (lane == 0) {
    float z = d * INV_T;
    float align   = logsig_neg(-z);
    float uniform = rowsum[n] * (1.0f / (float)M_);
    out[n]          = align + NEG_W * uniform;
    out[N_ + n]     = align;
    out[2 * N_ + n] = uniform;
  }
}

extern "C" void kernel_launch(void* const* d_in, const int* in_sizes, int n_in,
                              void* d_out, int out_size, void* d_ws,
                              size_t ws_size, hipStream_t stream) {
  const float* ref = (const float*)d_in[0];
  const float* pos = (const float*)d_in[1];
  const float* neg = (const float*)d_in[2];
  float* out = (float*)d_out;

  float* rowsum = (float*)d_ws;                                   // 32 KB
  unsigned char* a8 = (unsigned char*)d_ws + 32768;               // 4 MB
  unsigned char* b8 = a8 + (size_t)N_ * D_;                       // 4 MB

  hipMemsetAsync(rowsum, 0, N_ * sizeof(float), stream);
  cvt_pack<<<2048, 256, 0, stream>>>(ref, neg, a8, b8);
  nce_gemm<<<4096, 256, 0, stream>>>(a8, b8, rowsum);
  nce_combine<<<N_ / 4, 256, 0, stream>>>(ref, pos, rowsum, out);
}